// Round 1
// baseline (1548.396 us; speedup 1.0000x reference)
//
#include <hip/hip_runtime.h>
#include <cstdint>
#include <cstddef>

#define T_N    32768
#define N_SEG  2048
#define DSEQ   128
#define DLSTM  512
#define DX     512
#define DPROJ  1024
#define KDIM   640      // DLSTM + DSEQ
#define BCH    16       // chains per workgroup
#define OUTW   2048

// ---------------- kernel 1: segment boundaries ----------------
__global__ void seg_bounds_kernel(const int* __restrict__ masks,
                                  int* __restrict__ seg_start,
                                  int* __restrict__ seg_end) {
  int t = blockIdx.x * blockDim.x + threadIdx.x;
  if (t >= T_N) return;
  int m = masks[t];
  if (t == 0 || masks[t - 1] != m) seg_start[m] = t;
  if (t == T_N - 1 || masks[t + 1] != m) seg_end[m] = t + 1;
}

// ---------------- kernel 2: bitonic sort segs by length desc ----------------
__global__ __launch_bounds__(1024) void sort_kernel(const int* __restrict__ seg_start,
                                                    const int* __restrict__ seg_end,
                                                    int* __restrict__ sorted_ids) {
  __shared__ int key[N_SEG];
  __shared__ int val[N_SEG];
  const int tid = threadIdx.x;
  for (int i = tid; i < N_SEG; i += 1024) {
    key[i] = seg_end[i] - seg_start[i];
    val[i] = i;
  }
  __syncthreads();
  for (int size = 2; size <= N_SEG; size <<= 1) {
    for (int stride = size >> 1; stride > 0; stride >>= 1) {
      int lo = ((tid & ~(stride - 1)) << 1) | (tid & (stride - 1));
      int hi = lo | stride;
      bool asc = (lo & size) != 0;
      int klo = key[lo], khi = key[hi];
      bool sw = asc ? (klo > khi) : (klo < khi);
      if (sw) {
        key[lo] = khi; key[hi] = klo;
        int v = val[lo]; val[lo] = val[hi]; val[hi] = v;
      }
      __syncthreads();
    }
  }
  for (int i = tid; i < N_SEG; i += 1024) sorted_ids[i] = val[i];
}

// ---------------- kernel 3: build transposed fused weights ----------------
// Wt[dir][k][d] = (k < 512) ? W_hh_dir[d][k] : W_ih_dir[d][k-512]
__global__ void build_wt_kernel(const float* __restrict__ Whh_f, const float* __restrict__ Wih_f,
                                const float* __restrict__ Whh_b, const float* __restrict__ Wih_b,
                                float* __restrict__ Wt) {
  int idx = blockIdx.x * 256 + threadIdx.x;
  if (idx >= 2 * KDIM * DLSTM) return;
  int dir = idx / (KDIM * DLSTM);
  int rem = idx % (KDIM * DLSTM);
  int k = rem / DLSTM, d = rem % DLSTM;
  const float* Whh = dir ? Whh_b : Whh_f;
  const float* Wih = dir ? Wih_b : Wih_f;
  Wt[idx] = (k < DLSTM) ? Whh[d * DLSTM + k] : Wih[d * DSEQ + (k - DLSTM)];
}

// ---------------- kernel 4: out[:,0:1024] = x @ Wx^T + bx ----------------
#define TM 64
#define TN 64
#define TK 16
__global__ __launch_bounds__(256) void proj_kernel(const float* __restrict__ x,
                                                   const float* __restrict__ Wx,
                                                   const float* __restrict__ bx,
                                                   float* __restrict__ out) {
  __shared__ float As[TM][TK + 1];
  __shared__ float Bs[TN][TK + 1];
  const int tx = threadIdx.x & 15, ty = threadIdx.x >> 4;
  const int m0 = blockIdx.x * TM, n0 = blockIdx.y * TN;
  const int lrow = threadIdx.x >> 2, lk = (threadIdx.x & 3) * 4;
  float acc[4][4] = {};
  for (int k0 = 0; k0 < DX; k0 += TK) {
    __syncthreads();
    *(float4*)&As[lrow][lk] = *(const float4*)&x[(size_t)(m0 + lrow) * DX + k0 + lk];
    *(float4*)&Bs[lrow][lk] = *(const float4*)&Wx[(size_t)(n0 + lrow) * DX + k0 + lk];
    __syncthreads();
#pragma unroll
    for (int kk = 0; kk < TK; ++kk) {
      float a_[4], b_[4];
#pragma unroll
      for (int i = 0; i < 4; ++i) a_[i] = As[ty * 4 + i][kk];
#pragma unroll
      for (int j = 0; j < 4; ++j) b_[j] = Bs[tx * 4 + j][kk];
#pragma unroll
      for (int i = 0; i < 4; ++i)
#pragma unroll
        for (int j = 0; j < 4; ++j) acc[i][j] += a_[i] * b_[j];
    }
  }
#pragma unroll
  for (int i = 0; i < 4; ++i) {
#pragma unroll
    for (int j = 0; j < 4; ++j) {
      int m = m0 + ty * 4 + i, n = n0 + tx * 4 + j;
      out[(size_t)m * OUTW + n] = acc[i][j] + bx[n];
    }
  }
}

// ---------------- kernel 5: batched segmented RNN scan + pooling ----------------
// grid: (N_SEG/BCH, 2). block: 256. Wave w owns chains 4w..4w+3 of the batch.
// LDS A[c][0:512] = h_c (f32), A[c][512:640] = current seqs row for chain c.
__global__ __launch_bounds__(256) void scan_kernel(
    const float* __restrict__ seqs, const float* __restrict__ Wt,
    const float* __restrict__ b_f, const float* __restrict__ b_b,
    const int* __restrict__ sorted_ids, const int* __restrict__ seg_start_g,
    const int* __restrict__ seg_end_g, float* __restrict__ out) {
  const int dir = blockIdx.y;
  const int bb = blockIdx.x;
  const int tid = threadIdx.x;
  const int wave = tid >> 6;
  const int lane = tid & 63;
  const int d0 = lane * 8;  // this thread's 8 output dims (all 512 covered per wave)
  const float* __restrict__ W = Wt + (size_t)dir * KDIM * DLSTM;
  const float* __restrict__ bias = dir ? b_b : b_f;

  __shared__ float A[BCH][KDIM];
  __shared__ int s_start[BCH], s_len[BCH], s_sid[BCH];

  if (tid < BCH) {
    int sid = sorted_ids[bb * BCH + tid];
    s_sid[tid] = sid;
    int st = seg_start_g[sid];
    s_start[tid] = st;
    s_len[tid] = seg_end_g[sid] - st;
  }
  for (int i = tid; i < BCH * DLSTM; i += 256) {
    int c = i >> 9, d = i & 511;
    A[c][d] = 0.f;
  }
  __syncthreads();
  const int maxlen = s_len[0];  // sorted descending -> first is batch max

  float bias_r[8];
  *(float4*)&bias_r[0] = *(const float4*)&bias[d0];
  *(float4*)&bias_r[4] = *(const float4*)&bias[d0 + 4];

  float pool[4][8];
#pragma unroll
  for (int c4 = 0; c4 < 4; ++c4)
#pragma unroll
    for (int j = 0; j < 8; ++j) pool[c4][j] = 0.f;

  const int cs = tid >> 4;          // chain staged by this thread (wave-local: cs in [4*wave, 4*wave+3])
  const int js = (tid & 15) * 8;    // 8 floats of the seq row

  for (int s = 0; s < maxlen; ++s) {
    __syncthreads();  // prior k-loop reads done before overwriting x-part
    if (s < s_len[cs]) {
      int t = (dir == 0) ? (s_start[cs] + s) : (s_start[cs] + s_len[cs] - 1 - s);
      const float* sp = seqs + (size_t)t * DSEQ + js;
      float4 v0 = *(const float4*)sp;
      float4 v1 = *(const float4*)(sp + 4);
      *(float4*)&A[cs][DLSTM + js] = v0;
      *(float4*)&A[cs][DLSTM + js + 4] = v1;
    }
    __syncthreads();

    float acc[4][8];
#pragma unroll
    for (int c4 = 0; c4 < 4; ++c4)
#pragma unroll
      for (int j = 0; j < 8; ++j) acc[c4][j] = 0.f;

    for (int k = 0; k < KDIM; k += 4) {
      float w[4][8];
#pragma unroll
      for (int kk = 0; kk < 4; ++kk) {
        *(float4*)&w[kk][0] = *(const float4*)&W[(size_t)(k + kk) * DLSTM + d0];
        *(float4*)&w[kk][4] = *(const float4*)&W[(size_t)(k + kk) * DLSTM + d0 + 4];
      }
#pragma unroll
      for (int c4 = 0; c4 < 4; ++c4) {
        const float4 a = *(const float4*)&A[(wave << 2) + c4][k];
        const float av[4] = {a.x, a.y, a.z, a.w};
#pragma unroll
        for (int kk = 0; kk < 4; ++kk)
#pragma unroll
          for (int j = 0; j < 8; ++j) acc[c4][j] += av[kk] * w[kk][j];
      }
    }

#pragma unroll
    for (int c4 = 0; c4 < 4; ++c4) {
      const int c = (wave << 2) + c4;
      const bool act = s < s_len[c];
      float hn[8];
#pragma unroll
      for (int j = 0; j < 8; ++j) hn[j] = tanhf(acc[c4][j] + bias_r[j]);
      if (act) {
#pragma unroll
        for (int j = 0; j < 8; ++j) pool[c4][j] += hn[j];
        *(float4*)&A[c][d0]     = make_float4(hn[0], hn[1], hn[2], hn[3]);
        *(float4*)&A[c][d0 + 4] = make_float4(hn[4], hn[5], hn[6], hn[7]);
      }
    }
  }

  // epilogue: write pooled means
#pragma unroll
  for (int c4 = 0; c4 < 4; ++c4) {
    const int c = (wave << 2) + c4;
    const float inv = 1.0f / (float)s_len[c];
    float* op = out + (size_t)s_sid[c] * OUTW + DPROJ + dir * DLSTM + d0;
    *(float4*)op       = make_float4(pool[c4][0] * inv, pool[c4][1] * inv, pool[c4][2] * inv, pool[c4][3] * inv);
    *(float4*)(op + 4) = make_float4(pool[c4][4] * inv, pool[c4][5] * inv, pool[c4][6] * inv, pool[c4][7] * inv);
  }
}

extern "C" void kernel_launch(void* const* d_in, const int* in_sizes, int n_in,
                              void* d_out, int out_size, void* d_ws, size_t ws_size,
                              hipStream_t stream) {
  const float* x     = (const float*)d_in[0];
  const float* seqs  = (const float*)d_in[1];
  const int*   masks = (const int*)d_in[2];
  const float* Wih_f = (const float*)d_in[3];
  const float* Whh_f = (const float*)d_in[4];
  const float* b_f   = (const float*)d_in[5];
  const float* Wih_b = (const float*)d_in[6];
  const float* Whh_b = (const float*)d_in[7];
  const float* b_b   = (const float*)d_in[8];
  const float* Wx    = (const float*)d_in[9];
  const float* bx    = (const float*)d_in[10];
  float* out = (float*)d_out;

  char* ws = (char*)d_ws;
  float* Wt       = (float*)ws;  // 2*640*512 f32 = 2.5 MB
  int* seg_start  = (int*)(ws + (size_t)2 * KDIM * DLSTM * sizeof(float));
  int* seg_end    = seg_start + N_SEG;
  int* sorted_ids = seg_end + N_SEG;

  seg_bounds_kernel<<<T_N / 256, 256, 0, stream>>>(masks, seg_start, seg_end);
  sort_kernel<<<1, 1024, 0, stream>>>(seg_start, seg_end, sorted_ids);
  build_wt_kernel<<<(2 * KDIM * DLSTM + 255) / 256, 256, 0, stream>>>(Whh_f, Wih_f, Whh_b, Wih_b, Wt);
  proj_kernel<<<dim3(N_SEG / TM, DPROJ / TN), 256, 0, stream>>>(x, Wx, bx, out);
  scan_kernel<<<dim3(N_SEG / BCH, 2), 256, 0, stream>>>(seqs, Wt, b_f, b_b, sorted_ids,
                                                        seg_start, seg_end, out);
}

// Round 2
// 633.366 us; speedup vs baseline: 2.4447x; 2.4447x over previous
//
#include <hip/hip_runtime.h>
#include <cstdint>
#include <cstddef>

#define T_N    32768
#define N_SEG  2048
#define DSEQ   128
#define DLSTM  512
#define DX     512
#define DPROJ  1024
#define KDIM   640      // DLSTM + DSEQ
#define BCH    16       // chains per workgroup (= MFMA M)
#define OUTW   2048
#define KT_CNT 20       // KDIM / 32
#define AS     648      // LDS row stride (bf16 elems), 16B-aligned, breaks pow2

typedef __attribute__((ext_vector_type(8))) short short8;
typedef __attribute__((ext_vector_type(4))) float f32x4;

__device__ inline unsigned short f2b(float f) {
  unsigned int u = __float_as_uint(f);
  unsigned int r = (u + 0x7FFFu + ((u >> 16) & 1u)) >> 16;
  return (unsigned short)r;
}

// ---------------- kernel 1: segment boundaries ----------------
__global__ void seg_bounds_kernel(const int* __restrict__ masks,
                                  int* __restrict__ seg_start,
                                  int* __restrict__ seg_end) {
  int t = blockIdx.x * blockDim.x + threadIdx.x;
  if (t >= T_N) return;
  int m = masks[t];
  if (t == 0 || masks[t - 1] != m) seg_start[m] = t;
  if (t == T_N - 1 || masks[t + 1] != m) seg_end[m] = t + 1;
}

// ---------------- kernel 2: bitonic sort segs by length desc ----------------
__global__ __launch_bounds__(1024) void sort_kernel(const int* __restrict__ seg_start,
                                                    const int* __restrict__ seg_end,
                                                    int* __restrict__ sorted_ids) {
  __shared__ int key[N_SEG];
  __shared__ int val[N_SEG];
  const int tid = threadIdx.x;
  for (int i = tid; i < N_SEG; i += 1024) {
    key[i] = seg_end[i] - seg_start[i];
    val[i] = i;
  }
  __syncthreads();
  for (int size = 2; size <= N_SEG; size <<= 1) {
    for (int stride = size >> 1; stride > 0; stride >>= 1) {
      int lo = ((tid & ~(stride - 1)) << 1) | (tid & (stride - 1));
      int hi = lo | stride;
      bool asc = (lo & size) != 0;
      int klo = key[lo], khi = key[hi];
      bool sw = asc ? (klo > khi) : (klo < khi);
      if (sw) {
        key[lo] = khi; key[hi] = klo;
        int v = val[lo]; val[lo] = val[hi]; val[hi] = v;
      }
      __syncthreads();
    }
  }
  for (int i = tid; i < N_SEG; i += 1024) sorted_ids[i] = val[i];
}

// ---------------- kernel 3: build B-fragment-ordered bf16 weights ----------------
// WtB[dir][ntg(32)][kt(20)][lane(64)][8] ; packet for lane l:
//   k = kt*32 + (l>>4)*8 + r ; n = ntg*16 + (l&15)
//   src = k<512 ? W_hh[n][k] : W_ih[n][k-512]
__global__ void build_wtb_kernel(const float* __restrict__ Whh_f, const float* __restrict__ Wih_f,
                                 const float* __restrict__ Whh_b, const float* __restrict__ Wih_b,
                                 unsigned short* __restrict__ WtB) {
  int id = blockIdx.x * 256 + threadIdx.x;   // one packet per thread
  if (id >= 2 * 32 * KT_CNT * 64) return;
  int dir = id / (32 * KT_CNT * 64);
  int rem = id % (32 * KT_CNT * 64);
  int ntg = rem / (KT_CNT * 64);
  int rem2 = rem % (KT_CNT * 64);
  int kt = rem2 / 64;
  int lane = rem2 % 64;
  int k0 = kt * 32 + (lane >> 4) * 8;
  int n = ntg * 16 + (lane & 15);
  const float* Whh = dir ? Whh_b : Whh_f;
  const float* Wih = dir ? Wih_b : Wih_f;
  unsigned short pkt[8];
#pragma unroll
  for (int r = 0; r < 8; ++r) {
    int k = k0 + r;
    float v = (k < DLSTM) ? Whh[(size_t)n * DLSTM + k] : Wih[(size_t)n * DSEQ + (k - DLSTM)];
    pkt[r] = f2b(v);
  }
  *(short8*)&WtB[(size_t)id * 8] = *(short8*)pkt;
}

// ---------------- kernel 4: out[:,0:1024] = x @ Wx^T + bx ----------------
#define TM 64
#define TN 64
#define TK 16
__global__ __launch_bounds__(256) void proj_kernel(const float* __restrict__ x,
                                                   const float* __restrict__ Wx,
                                                   const float* __restrict__ bx,
                                                   float* __restrict__ out) {
  __shared__ float As[TM][TK + 1];
  __shared__ float Bs[TN][TK + 1];
  const int tx = threadIdx.x & 15, ty = threadIdx.x >> 4;
  const int m0 = blockIdx.x * TM, n0 = blockIdx.y * TN;
  const int lrow = threadIdx.x >> 2, lk = (threadIdx.x & 3) * 4;
  float acc[4][4] = {};
  for (int k0 = 0; k0 < DX; k0 += TK) {
    __syncthreads();
    *(float4*)&As[lrow][lk] = *(const float4*)&x[(size_t)(m0 + lrow) * DX + k0 + lk];
    *(float4*)&Bs[lrow][lk] = *(const float4*)&Wx[(size_t)(n0 + lrow) * DX + k0 + lk];
    __syncthreads();
#pragma unroll
    for (int kk = 0; kk < TK; ++kk) {
      float a_[4], b_[4];
#pragma unroll
      for (int i = 0; i < 4; ++i) a_[i] = As[ty * 4 + i][kk];
#pragma unroll
      for (int j = 0; j < 4; ++j) b_[j] = Bs[tx * 4 + j][kk];
#pragma unroll
      for (int i = 0; i < 4; ++i)
#pragma unroll
        for (int j = 0; j < 4; ++j) acc[i][j] += a_[i] * b_[j];
    }
  }
#pragma unroll
  for (int i = 0; i < 4; ++i) {
#pragma unroll
    for (int j = 0; j < 4; ++j) {
      int m = m0 + ty * 4 + i, n = n0 + tx * 4 + j;
      out[(size_t)m * OUTW + n] = acc[i][j] + bx[n];
    }
  }
}

// ---------------- kernel 5: MFMA batched segmented RNN scan + pooling ----------------
// grid (128, 2); block 256 (4 waves). Wave w owns output cols [w*128, w*128+128).
// LDS A[c][0:512]=h (bf16), A[c][512:640]=x row (bf16). M=16 chains per WG.
__global__ __launch_bounds__(256) void scan_mfma_kernel(
    const float* __restrict__ seqs, const unsigned short* __restrict__ WtB,
    const float* __restrict__ b_f, const float* __restrict__ b_b,
    const int* __restrict__ sorted_ids, const int* __restrict__ seg_start_g,
    const int* __restrict__ seg_end_g, float* __restrict__ out) {
  const int dir = blockIdx.y;
  const int bb = blockIdx.x;
  const int tid = threadIdx.x;
  const int wave = tid >> 6;
  const int lane = tid & 63;
  const int rowA = lane & 15;      // A-frag row (chain)
  const int kgrp = lane >> 4;      // k-group of 8

  __shared__ unsigned short A[BCH][AS];
  __shared__ int s_start[BCH], s_len[BCH], s_sid[BCH];

  if (tid < BCH) {
    int sid = sorted_ids[bb * BCH + tid];
    s_sid[tid] = sid;
    int st = seg_start_g[sid];
    s_start[tid] = st;
    s_len[tid] = seg_end_g[sid] - st;
  }
  // zero h-part
  for (int idx = tid; idx < BCH * (DLSTM / 8); idx += 256) {
    int row = idx >> 6, col8 = (idx & 63) * 8;
    short8 z = {0, 0, 0, 0, 0, 0, 0, 0};
    *(short8*)&A[row][col8] = z;
  }
  __syncthreads();
  const int maxlen = s_len[0];  // sorted desc

  const float* __restrict__ bias = dir ? b_b : b_f;
  float bias_r[8];
#pragma unroll
  for (int nt = 0; nt < 8; ++nt)
    bias_r[nt] = bias[wave * 128 + nt * 16 + (lane & 15)];

  int lenD[4];
#pragma unroll
  for (int r = 0; r < 4; ++r) lenD[r] = s_len[kgrp * 4 + r];

  float pool[8][4];
#pragma unroll
  for (int nt = 0; nt < 8; ++nt)
#pragma unroll
    for (int r = 0; r < 4; ++r) pool[nt][r] = 0.f;

  // this wave's weight base: ntg = wave*8 + nt
  const unsigned short* __restrict__ WB =
      WtB + (((size_t)dir * 32 + wave * 8) * KT_CNT) * 512;  // 512 = 64 lanes * 8

  const int cs = tid >> 4;          // staging chain
  const int js = (tid & 15) * 8;    // 8 floats of seq row
  const int cs_len = s_len[cs];
  const int cs_start = s_start[cs];

  for (int s = 0; s < maxlen; ++s) {
    __syncthreads();  // prior reads of A done before overwriting x-part
    if (s < cs_len) {
      int t = dir ? (cs_start + cs_len - 1 - s) : (cs_start + s);
      const float* sp = seqs + (size_t)t * DSEQ + js;
      float4 v0 = *(const float4*)sp;
      float4 v1 = *(const float4*)(sp + 4);
      unsigned short p[8] = {f2b(v0.x), f2b(v0.y), f2b(v0.z), f2b(v0.w),
                             f2b(v1.x), f2b(v1.y), f2b(v1.z), f2b(v1.w)};
      *(short8*)&A[cs][DLSTM + js] = *(short8*)p;
    }
    __syncthreads();

    f32x4 acc[8];
#pragma unroll
    for (int nt = 0; nt < 8; ++nt) acc[nt] = (f32x4){0.f, 0.f, 0.f, 0.f};

    for (int kt = 0; kt < KT_CNT; ++kt) {
      short8 a = *(const short8*)&A[rowA][kt * 32 + kgrp * 8];
      const unsigned short* wp = WB + (size_t)kt * 512 + lane * 8;
#pragma unroll
      for (int nt = 0; nt < 8; ++nt) {
        short8 b = *(const short8*)(wp + (size_t)nt * KT_CNT * 512);
        acc[nt] = __builtin_amdgcn_mfma_f32_16x16x32_bf16(a, b, acc[nt], 0, 0, 0);
      }
    }
    __syncthreads();  // all waves done reading A before h write-back

#pragma unroll
    for (int nt = 0; nt < 8; ++nt) {
      const int coln = wave * 128 + nt * 16 + (lane & 15);
#pragma unroll
      for (int r = 0; r < 4; ++r) {
        if (s < lenD[r]) {
          float h = tanhf(acc[nt][r] + bias_r[nt]);
          pool[nt][r] += h;
          A[kgrp * 4 + r][coln] = f2b(h);
        }
      }
    }
  }

  // epilogue: pooled means
#pragma unroll
  for (int nt = 0; nt < 8; ++nt) {
    const int coln = wave * 128 + nt * 16 + (lane & 15);
#pragma unroll
    for (int r = 0; r < 4; ++r) {
      const int row = kgrp * 4 + r;
      out[(size_t)s_sid[row] * OUTW + DPROJ + dir * DLSTM + coln] =
          pool[nt][r] / (float)lenD[r];
    }
  }
}

extern "C" void kernel_launch(void* const* d_in, const int* in_sizes, int n_in,
                              void* d_out, int out_size, void* d_ws, size_t ws_size,
                              hipStream_t stream) {
  const float* x     = (const float*)d_in[0];
  const float* seqs  = (const float*)d_in[1];
  const int*   masks = (const int*)d_in[2];
  const float* Wih_f = (const float*)d_in[3];
  const float* Whh_f = (const float*)d_in[4];
  const float* b_f   = (const float*)d_in[5];
  const float* Wih_b = (const float*)d_in[6];
  const float* Whh_b = (const float*)d_in[7];
  const float* b_b   = (const float*)d_in[8];
  const float* Wx    = (const float*)d_in[9];
  const float* bx    = (const float*)d_in[10];
  float* out = (float*)d_out;

  char* ws = (char*)d_ws;
  unsigned short* WtB = (unsigned short*)ws;                // 2*640*512 bf16 = 1.31 MB
  size_t wtb_bytes = (size_t)2 * KDIM * DLSTM * sizeof(unsigned short);
  int* seg_start  = (int*)(ws + wtb_bytes);
  int* seg_end    = seg_start + N_SEG;
  int* sorted_ids = seg_end + N_SEG;

  seg_bounds_kernel<<<T_N / 256, 256, 0, stream>>>(masks, seg_start, seg_end);
  sort_kernel<<<1, 1024, 0, stream>>>(seg_start, seg_end, sorted_ids);
  {
    int npkt = 2 * 32 * KT_CNT * 64;
    build_wtb_kernel<<<(npkt + 255) / 256, 256, 0, stream>>>(Whh_f, Wih_f, Whh_b, Wih_b, WtB);
  }
  proj_kernel<<<dim3(N_SEG / TM, DPROJ / TN), 256, 0, stream>>>(x, Wx, bx, out);
  scan_mfma_kernel<<<dim3(N_SEG / BCH, 2), 256, 0, stream>>>(seqs, WtB, b_f, b_b, sorted_ids,
                                                             seg_start, seg_end, out);
}

// Round 3
// 178.028 us; speedup vs baseline: 8.6975x; 3.5577x over previous
//
#include <hip/hip_runtime.h>
#include <cstdint>
#include <cstddef>

#define T_N    32768
#define N_SEG  2048
#define DSEQ   128
#define DLSTM  512
#define DX     512
#define DPROJ  1024
#define OUTW   2048
#define BCH    16
#define KDIM   640
#define KT_CNT 20
#define AS     648
#define HSTR   528      // int8 h row stride (8B aligned, breaks pow2)
#define WSCALE 2873.6827f            // 127 * sqrt(512)
#define DEQF   (1.0f/(2873.6827f*127.0f))

typedef __attribute__((ext_vector_type(8))) short short8;
typedef __attribute__((ext_vector_type(4))) float f32x4;
typedef __attribute__((ext_vector_type(4))) int i32x4;

__device__ inline unsigned short f2b(float f) {
  unsigned int u = __float_as_uint(f);
  unsigned int r = (u + 0x7FFFu + ((u >> 16) & 1u)) >> 16;
  return (unsigned short)r;
}
__device__ inline float b2f(unsigned short u) {
  return __uint_as_float(((unsigned int)u) << 16);
}

// ---------------- segment boundaries ----------------
__global__ void seg_bounds_kernel(const int* __restrict__ masks,
                                  int* __restrict__ seg_start,
                                  int* __restrict__ seg_end) {
  int t = blockIdx.x * blockDim.x + threadIdx.x;
  if (t >= T_N) return;
  int m = masks[t];
  if (t == 0 || masks[t - 1] != m) seg_start[m] = t;
  if (t == T_N - 1 || masks[t + 1] != m) seg_end[m] = t + 1;
}

// ---------------- bitonic sort by length desc ----------------
__global__ __launch_bounds__(1024) void sort_kernel(const int* __restrict__ seg_start,
                                                    const int* __restrict__ seg_end,
                                                    int* __restrict__ sorted_ids) {
  __shared__ int key[N_SEG];
  __shared__ int val[N_SEG];
  const int tid = threadIdx.x;
  for (int i = tid; i < N_SEG; i += 1024) {
    key[i] = seg_end[i] - seg_start[i];
    val[i] = i;
  }
  __syncthreads();
  for (int size = 2; size <= N_SEG; size <<= 1) {
    for (int stride = size >> 1; stride > 0; stride >>= 1) {
      int lo = ((tid & ~(stride - 1)) << 1) | (tid & (stride - 1));
      int hi = lo | stride;
      bool asc = (lo & size) != 0;
      int klo = key[lo], khi = key[hi];
      bool sw = asc ? (klo > khi) : (klo < khi);
      if (sw) {
        key[lo] = khi; key[hi] = klo;
        int v = val[lo]; val[lo] = val[hi]; val[hi] = v;
      }
      __syncthreads();
    }
  }
  for (int i = tid; i < N_SEG; i += 1024) sorted_ids[i] = val[i];
}

// ---------------- pack W_hh to int8 B-fragments ----------------
// id = ((dir*32 + ntg)*16 + kt)*64 + lane ; n = ntg*16+(lane&15); k = kt*32+(lane>>4)*8+r
__global__ void pack_w8_kernel(const float* __restrict__ Whh_f, const float* __restrict__ Whh_b,
                               signed char* __restrict__ W8) {
  int id = blockIdx.x * 256 + threadIdx.x;
  if (id >= 2 * 32 * 16 * 64) return;
  int dir = id >> 15;
  int rem = id & 32767;
  int ntg = rem >> 10;
  int kt = (rem >> 6) & 15;
  int lane = rem & 63;
  int n = ntg * 16 + (lane & 15);
  int k0 = kt * 32 + (lane >> 4) * 8;
  const float* W = dir ? Whh_b : Whh_f;
  signed char pkt[8];
#pragma unroll
  for (int r = 0; r < 8; ++r) {
    float w = W[(size_t)n * DLSTM + k0 + r];
    int q = (int)rintf(w * WSCALE);
    q = q > 127 ? 127 : (q < -127 ? -127 : q);
    pkt[r] = (signed char)q;
  }
  long v;
  __builtin_memcpy(&v, pkt, 8);
  *(long*)&W8[(size_t)id * 8] = v;
}

// ---------------- generic bf16 MFMA GEMM: C = A(f32,MxK) @ B(f32,NxK)^T + bias ----------------
// B rows: n<nsplit -> B0[n], else B1[n-nsplit]; bias likewise.
template<bool BF16OUT>
__global__ __launch_bounds__(256) void gemm_bt_kernel(
    const float* __restrict__ A, const float* __restrict__ B0, const float* __restrict__ B1,
    int nsplit, const float* __restrict__ bias0, const float* __restrict__ bias1,
    int K, void* __restrict__ C, int ldc) {
  __shared__ unsigned short As[128][40];
  __shared__ unsigned short Bs[128][40];
  const int tid = threadIdx.x;
  const int m0 = blockIdx.x * 128, n0 = blockIdx.y * 128;
  const int wave = tid >> 6, lane = tid & 63;
  const int wm = (wave >> 1) * 64, wn = (wave & 1) * 64;
  const int rowA = lane & 15, kgrp = lane >> 4;
  const int lrow = tid >> 1, lkc = (tid & 1) * 16;

  f32x4 acc[4][4];
#pragma unroll
  for (int i = 0; i < 4; ++i)
#pragma unroll
    for (int j = 0; j < 4; ++j) acc[i][j] = (f32x4){0.f, 0.f, 0.f, 0.f};

  for (int k0 = 0; k0 < K; k0 += 32) {
    __syncthreads();
    {
      const float* ap = A + (size_t)(m0 + lrow) * K + k0 + lkc;
      unsigned short pa[16];
#pragma unroll
      for (int q = 0; q < 4; ++q) {
        float4 v = *(const float4*)(ap + q * 4);
        pa[q * 4 + 0] = f2b(v.x); pa[q * 4 + 1] = f2b(v.y);
        pa[q * 4 + 2] = f2b(v.z); pa[q * 4 + 3] = f2b(v.w);
      }
      *(short8*)&As[lrow][lkc] = *(short8*)&pa[0];
      *(short8*)&As[lrow][lkc + 8] = *(short8*)&pa[8];

      int n = n0 + lrow;
      const float* bp;
      if (n < nsplit) bp = B0 + (size_t)n * K;
      else            bp = B1 + (size_t)(n - nsplit) * K;
      bp += k0 + lkc;
      unsigned short pb[16];
#pragma unroll
      for (int q = 0; q < 4; ++q) {
        float4 v = *(const float4*)(bp + q * 4);
        pb[q * 4 + 0] = f2b(v.x); pb[q * 4 + 1] = f2b(v.y);
        pb[q * 4 + 2] = f2b(v.z); pb[q * 4 + 3] = f2b(v.w);
      }
      *(short8*)&Bs[lrow][lkc] = *(short8*)&pb[0];
      *(short8*)&Bs[lrow][lkc + 8] = *(short8*)&pb[8];
    }
    __syncthreads();
    short8 af[4], bf[4];
#pragma unroll
    for (int mt = 0; mt < 4; ++mt) af[mt] = *(const short8*)&As[wm + mt * 16 + rowA][kgrp * 8];
#pragma unroll
    for (int nt = 0; nt < 4; ++nt) bf[nt] = *(const short8*)&Bs[wn + nt * 16 + rowA][kgrp * 8];
#pragma unroll
    for (int mt = 0; mt < 4; ++mt)
#pragma unroll
      for (int nt = 0; nt < 4; ++nt)
        acc[mt][nt] = __builtin_amdgcn_mfma_f32_16x16x32_bf16(af[mt], bf[nt], acc[mt][nt], 0, 0, 0);
  }

#pragma unroll
  for (int mt = 0; mt < 4; ++mt)
#pragma unroll
    for (int nt = 0; nt < 4; ++nt) {
      int n = n0 + wn + nt * 16 + rowA;
      float bv = (n < nsplit) ? bias0[n] : bias1[n - nsplit];
#pragma unroll
      for (int r = 0; r < 4; ++r) {
        int m = m0 + wm + mt * 16 + kgrp * 4 + r;
        float v = acc[mt][nt][r] + bv;
        if (BF16OUT) ((unsigned short*)C)[(size_t)m * ldc + n] = f2b(v);
        else         ((float*)C)[(size_t)m * ldc + n] = v;
      }
    }
}

// ---------------- scan: int8 register-resident weights ----------------
__global__ __launch_bounds__(512, 2) void scan_i8_kernel(
    const unsigned short* __restrict__ pre,   // [T][1024] bf16 (cols: dir*512+col)
    const signed char* __restrict__ W8,
    const int* __restrict__ sorted_ids, const int* __restrict__ seg_start_g,
    const int* __restrict__ seg_end_g, float* __restrict__ out) {
  const int dir = blockIdx.y, bb = blockIdx.x;
  const int tid = threadIdx.x;
  const int wave = tid >> 6, lane = tid & 63;
  const int rowA = lane & 15, kgrp = lane >> 4;
  const int colbase = wave * 64;

  __shared__ signed char H[BCH][HSTR];
  __shared__ int s_start[BCH], s_len[BCH], s_sid[BCH];

  if (tid < BCH) {
    int sid = sorted_ids[bb * BCH + tid];
    s_sid[tid] = sid;
    int st = seg_start_g[sid];
    s_start[tid] = st;
    s_len[tid] = seg_end_g[sid] - st;
  }
  for (int i = tid; i < BCH * 32; i += 512) {  // 16B chunks over H[c][0:512]
    int c = i >> 5, o = (i & 31) * 16;
    *(int4*)&H[c][o] = make_int4(0, 0, 0, 0);
  }

  // load this wave's weight slice into registers: 4 ntg x 16 kt fragments
  long wreg[4][16];
  const signed char* wb = W8 + ((size_t)(dir * 32 + wave * 4) * 16) * 512;
#pragma unroll
  for (int nt = 0; nt < 4; ++nt)
#pragma unroll
    for (int kt = 0; kt < 16; ++kt)
      wreg[nt][kt] = *(const long*)(wb + (size_t)((nt * 16 + kt) * 64 + lane) * 8);

  __syncthreads();
  const int maxlen = s_len[0];

  int lenD[4], startD[4];
#pragma unroll
  for (int r = 0; r < 4; ++r) {
    lenD[r] = s_len[kgrp * 4 + r];
    startD[r] = s_start[kgrp * 4 + r];
  }

  float pool[4][4];
#pragma unroll
  for (int nt = 0; nt < 4; ++nt)
#pragma unroll
    for (int r = 0; r < 4; ++r) pool[nt][r] = 0.f;

  for (int s = 0; s < maxlen; ++s) {
    // issue pre loads early (consumed after MFMA)
    unsigned short pu[4][4];
#pragma unroll
    for (int r = 0; r < 4; ++r) {
      int t = (s < lenD[r]) ? (dir ? (startD[r] + lenD[r] - 1 - s) : (startD[r] + s))
                            : startD[r];
      const unsigned short* pp = pre + (size_t)t * 1024 + dir * 512 + colbase + rowA;
#pragma unroll
      for (int nt = 0; nt < 4; ++nt) pu[nt][r] = pp[nt * 16];
    }

    i32x4 acc[4];
#pragma unroll
    for (int nt = 0; nt < 4; ++nt) acc[nt] = (i32x4){0, 0, 0, 0};
#pragma unroll
    for (int kt = 0; kt < 16; ++kt) {
      long a = *(const long*)&H[rowA][kt * 32 + kgrp * 8];
#pragma unroll
      for (int nt = 0; nt < 4; ++nt)
        acc[nt] = __builtin_amdgcn_mfma_i32_16x16x32_i8(a, wreg[nt][kt], acc[nt], 0, 0, 0);
    }
    __syncthreads();  // all reads of H done

#pragma unroll
    for (int nt = 0; nt < 4; ++nt) {
      const int col = colbase + nt * 16 + rowA;
#pragma unroll
      for (int r = 0; r < 4; ++r) {
        if (s < lenD[r]) {
          float a = (float)acc[nt][r] * DEQF + b2f(pu[nt][r]);
          float xc = fminf(fmaxf(a, -9.f), 9.f);
          float e = __expf(2.f * xc);
          float h = 1.f - 2.f / (e + 1.f);
          pool[nt][r] += h;
          H[kgrp * 4 + r][col] = (signed char)(int)rintf(h * 127.f);
        }
      }
    }
    __syncthreads();  // writes visible before next step's reads
  }

#pragma unroll
  for (int nt = 0; nt < 4; ++nt)
#pragma unroll
    for (int r = 0; r < 4; ++r) {
      const int c = kgrp * 4 + r;
      out[(size_t)s_sid[c] * OUTW + DPROJ + dir * DLSTM + colbase + nt * 16 + rowA] =
          pool[nt][r] / (float)lenD[r];
    }
}

// ================= fallback (round-2 bf16 streaming scan) =================
__global__ void build_wtb_kernel(const float* __restrict__ Whh_f, const float* __restrict__ Wih_f,
                                 const float* __restrict__ Whh_b, const float* __restrict__ Wih_b,
                                 unsigned short* __restrict__ WtB) {
  int id = blockIdx.x * 256 + threadIdx.x;
  if (id >= 2 * 32 * KT_CNT * 64) return;
  int dir = id / (32 * KT_CNT * 64);
  int rem = id % (32 * KT_CNT * 64);
  int ntg = rem / (KT_CNT * 64);
  int rem2 = rem % (KT_CNT * 64);
  int kt = rem2 / 64;
  int lane = rem2 % 64;
  int k0 = kt * 32 + (lane >> 4) * 8;
  int n = ntg * 16 + (lane & 15);
  const float* Whh = dir ? Whh_b : Whh_f;
  const float* Wih = dir ? Wih_b : Wih_f;
  unsigned short pkt[8];
#pragma unroll
  for (int r = 0; r < 8; ++r) {
    int k = k0 + r;
    float v = (k < DLSTM) ? Whh[(size_t)n * DLSTM + k] : Wih[(size_t)n * DSEQ + (k - DLSTM)];
    pkt[r] = f2b(v);
  }
  *(short8*)&WtB[(size_t)id * 8] = *(short8*)pkt;
}

__global__ __launch_bounds__(256) void scan_mfma_kernel(
    const float* __restrict__ seqs, const unsigned short* __restrict__ WtB,
    const float* __restrict__ b_f, const float* __restrict__ b_b,
    const int* __restrict__ sorted_ids, const int* __restrict__ seg_start_g,
    const int* __restrict__ seg_end_g, float* __restrict__ out) {
  const int dir = blockIdx.y;
  const int bb = blockIdx.x;
  const int tid = threadIdx.x;
  const int wave = tid >> 6;
  const int lane = tid & 63;
  const int rowA = lane & 15;
  const int kgrp = lane >> 4;

  __shared__ unsigned short A[BCH][AS];
  __shared__ int s_start[BCH], s_len[BCH], s_sid[BCH];

  if (tid < BCH) {
    int sid = sorted_ids[bb * BCH + tid];
    s_sid[tid] = sid;
    int st = seg_start_g[sid];
    s_start[tid] = st;
    s_len[tid] = seg_end_g[sid] - st;
  }
  for (int idx = tid; idx < BCH * (DLSTM / 8); idx += 256) {
    int row = idx >> 6, col8 = (idx & 63) * 8;
    short8 z = {0, 0, 0, 0, 0, 0, 0, 0};
    *(short8*)&A[row][col8] = z;
  }
  __syncthreads();
  const int maxlen = s_len[0];

  const float* __restrict__ bias = dir ? b_b : b_f;
  float bias_r[8];
#pragma unroll
  for (int nt = 0; nt < 8; ++nt)
    bias_r[nt] = bias[wave * 128 + nt * 16 + (lane & 15)];

  int lenD[4];
#pragma unroll
  for (int r = 0; r < 4; ++r) lenD[r] = s_len[kgrp * 4 + r];

  float pool[8][4];
#pragma unroll
  for (int nt = 0; nt < 8; ++nt)
#pragma unroll
    for (int r = 0; r < 4; ++r) pool[nt][r] = 0.f;

  const unsigned short* __restrict__ WB =
      WtB + (((size_t)dir * 32 + wave * 8) * KT_CNT) * 512;

  const int cs = tid >> 4;
  const int js = (tid & 15) * 8;
  const int cs_len = s_len[cs];
  const int cs_start = s_start[cs];

  for (int s = 0; s < maxlen; ++s) {
    __syncthreads();
    if (s < cs_len) {
      int t = dir ? (cs_start + cs_len - 1 - s) : (cs_start + s);
      const float* sp = seqs + (size_t)t * DSEQ + js;
      float4 v0 = *(const float4*)sp;
      float4 v1 = *(const float4*)(sp + 4);
      unsigned short p[8] = {f2b(v0.x), f2b(v0.y), f2b(v0.z), f2b(v0.w),
                             f2b(v1.x), f2b(v1.y), f2b(v1.z), f2b(v1.w)};
      *(short8*)&A[cs][DLSTM + js] = *(short8*)p;
    }
    __syncthreads();

    f32x4 acc[8];
#pragma unroll
    for (int nt = 0; nt < 8; ++nt) acc[nt] = (f32x4){0.f, 0.f, 0.f, 0.f};

    for (int kt = 0; kt < KT_CNT; ++kt) {
      short8 a = *(const short8*)&A[rowA][kt * 32 + kgrp * 8];
      const unsigned short* wp = WB + (size_t)kt * 512 + lane * 8;
#pragma unroll
      for (int nt = 0; nt < 8; ++nt) {
        short8 b = *(const short8*)(wp + (size_t)nt * KT_CNT * 512);
        acc[nt] = __builtin_amdgcn_mfma_f32_16x16x32_bf16(a, b, acc[nt], 0, 0, 0);
      }
    }
    __syncthreads();

#pragma unroll
    for (int nt = 0; nt < 8; ++nt) {
      const int coln = wave * 128 + nt * 16 + (lane & 15);
#pragma unroll
      for (int r = 0; r < 4; ++r) {
        if (s < lenD[r]) {
          float h = tanhf(acc[nt][r] + bias_r[nt]);
          pool[nt][r] += h;
          A[kgrp * 4 + r][coln] = f2b(h);
        }
      }
    }
  }

#pragma unroll
  for (int nt = 0; nt < 8; ++nt) {
    const int coln = wave * 128 + nt * 16 + (lane & 15);
#pragma unroll
    for (int r = 0; r < 4; ++r) {
      const int row = kgrp * 4 + r;
      out[(size_t)s_sid[row] * OUTW + DPROJ + dir * DLSTM + coln] =
          pool[nt][r] / (float)lenD[r];
    }
  }
}

extern "C" void kernel_launch(void* const* d_in, const int* in_sizes, int n_in,
                              void* d_out, int out_size, void* d_ws, size_t ws_size,
                              hipStream_t stream) {
  const float* x     = (const float*)d_in[0];
  const float* seqs  = (const float*)d_in[1];
  const int*   masks = (const int*)d_in[2];
  const float* Wih_f = (const float*)d_in[3];
  const float* Whh_f = (const float*)d_in[4];
  const float* b_f   = (const float*)d_in[5];
  const float* Wih_b = (const float*)d_in[6];
  const float* Whh_b = (const float*)d_in[7];
  const float* b_b   = (const float*)d_in[8];
  const float* Wx    = (const float*)d_in[9];
  const float* bx    = (const float*)d_in[10];
  float* out = (float*)d_out;

  char* ws = (char*)d_ws;
  const size_t pre_bytes = (size_t)T_N * 1024 * 2;   // 67.1 MB
  const size_t w8_bytes  = (size_t)2 * 512 * 512;    // 0.5 MB
  const size_t need = pre_bytes + w8_bytes + 3 * N_SEG * 4;

  if (ws_size >= need) {
    unsigned short* pre = (unsigned short*)ws;
    signed char* W8     = (signed char*)(ws + pre_bytes);
    int* seg_start      = (int*)(ws + pre_bytes + w8_bytes);
    int* seg_end        = seg_start + N_SEG;
    int* sorted_ids     = seg_end + N_SEG;

    seg_bounds_kernel<<<T_N / 256, 256, 0, stream>>>(masks, seg_start, seg_end);
    sort_kernel<<<1, 1024, 0, stream>>>(seg_start, seg_end, sorted_ids);
    pack_w8_kernel<<<(2 * 32 * 16 * 64) / 256, 256, 0, stream>>>(Whh_f, Whh_b, W8);
    // pre = seqs @ [Wih_f;Wih_b]^T + [b_f;b_b]  (bf16 out)
    gemm_bt_kernel<true><<<dim3(T_N / 128, 1024 / 128), 256, 0, stream>>>(
        seqs, Wih_f, Wih_b, 512, b_f, b_b, DSEQ, pre, 1024);
    // out[:,0:1024] = x @ Wx^T + bx  (f32 out)
    gemm_bt_kernel<false><<<dim3(N_SEG / 128, 1024 / 128), 256, 0, stream>>>(
        x, Wx, nullptr, 1 << 30, bx, nullptr, DX, out, OUTW);
    scan_i8_kernel<<<dim3(N_SEG / BCH, 2), 512, 0, stream>>>(
        pre, W8, sorted_ids, seg_start, seg_end, out);
  } else {
    // fallback: round-2 bf16 streaming path
    unsigned short* WtB = (unsigned short*)ws;
    size_t wtb_bytes = (size_t)2 * KDIM * DLSTM * sizeof(unsigned short);
    int* seg_start  = (int*)(ws + wtb_bytes);
    int* seg_end    = seg_start + N_SEG;
    int* sorted_ids = seg_end + N_SEG;

    seg_bounds_kernel<<<T_N / 256, 256, 0, stream>>>(masks, seg_start, seg_end);
    sort_kernel<<<1, 1024, 0, stream>>>(seg_start, seg_end, sorted_ids);
    build_wtb_kernel<<<(2 * 32 * KT_CNT * 64 + 255) / 256, 256, 0, stream>>>(
        Whh_f, Wih_f, Whh_b, Wih_b, WtB);
    gemm_bt_kernel<false><<<dim3(N_SEG / 128, 1024 / 128), 256, 0, stream>>>(
        x, Wx, nullptr, 1 << 30, bx, nullptr, DX, out, OUTW);
    scan_mfma_kernel<<<dim3(N_SEG / BCH, 2), 256, 0, stream>>>(
        seqs, WtB, b_f, b_b, sorted_ids, seg_start, seg_end, out);
  }
}

// Round 4
// 136.546 us; speedup vs baseline: 11.3397x; 1.3038x over previous
//
#include <hip/hip_runtime.h>
#include <cstdint>
#include <cstddef>

#define T_N    32768
#define N_SEG  2048
#define DSEQ   128
#define DLSTM  512
#define DX     512
#define DPROJ  1024
#define OUTW   2048
#define HSTR   520      // H row stride bytes (512+8): read banks optimal
#define WSCALE 2873.6827f                 // 127*sqrt(512)
#define LOG2E2 2.8853900817779268f        // 2*log2(e)
#define DEQ2   (2.8853900817779268f/(2873.6827f*127.0f))

typedef __attribute__((ext_vector_type(8))) short short8;
typedef __attribute__((ext_vector_type(4))) float f32x4;
typedef __attribute__((ext_vector_type(4))) int i32x4;

#if __has_builtin(__builtin_amdgcn_exp2f)
#define EXP2F(x) __builtin_amdgcn_exp2f(x)
#else
#define EXP2F(x) __expf((x) * 0.6931471805599453f)
#endif
#if __has_builtin(__builtin_amdgcn_rcpf)
#define RCPF(x) __builtin_amdgcn_rcpf(x)
#else
#define RCPF(x) (1.0f / (x))
#endif

__device__ inline unsigned short f2b(float f) {
  unsigned int u = __float_as_uint(f);
  unsigned int r = (u + 0x7FFFu + ((u >> 16) & 1u)) >> 16;
  return (unsigned short)r;
}

// ---------------- prep: segment boundaries + int8 weight pack (fused) ----------------
// blocks [0,128): seg bounds over T_N. blocks [128, 384): pack W8 fragments.
// W8 frag id = ((dir*32 + g)*16 + kt)*64 + lane ; row = g*16+(lane&15), k = kt*32+(lane>>4)*8+r
__global__ void prep_kernel(const int* __restrict__ masks,
                            int* __restrict__ seg_start, int* __restrict__ seg_end,
                            const float* __restrict__ Whh_f, const float* __restrict__ Whh_b,
                            signed char* __restrict__ W8) {
  const int bx = blockIdx.x;
  if (bx < T_N / 256) {
    int t = bx * 256 + threadIdx.x;
    int m = masks[t];
    if (t == 0 || masks[t - 1] != m) seg_start[m] = t;
    if (t == T_N - 1 || masks[t + 1] != m) seg_end[m] = t + 1;
  } else {
    int id = (bx - T_N / 256) * 256 + threadIdx.x;   // < 65536
    int dir = id >> 15;
    int rem = id & 32767;
    int g = rem >> 10;
    int kt = (rem >> 6) & 15;
    int lane = rem & 63;
    int n = g * 16 + (lane & 15);
    int k0 = kt * 32 + (lane >> 4) * 8;
    const float* W = dir ? Whh_b : Whh_f;
    signed char pkt[8];
#pragma unroll
    for (int r = 0; r < 8; ++r) {
      float w = W[(size_t)n * DLSTM + k0 + r];
      int q = (int)rintf(w * WSCALE);
      q = q > 127 ? 127 : (q < -127 ? -127 : q);
      pkt[r] = (signed char)q;
    }
    long v;
    __builtin_memcpy(&v, pkt, 8);
    *(long*)&W8[(size_t)id * 8] = v;
  }
}

// ---------------- counting sort of segments by length, descending ----------------
__global__ __launch_bounds__(1024) void csort_kernel(const int* __restrict__ seg_start,
                                                     const int* __restrict__ seg_end,
                                                     int* __restrict__ sorted_ids) {
  __shared__ int A_[2048];
  __shared__ int B_[2048];
  const int tid = threadIdx.x;
  for (int i = tid; i < 2048; i += 1024) A_[i] = 0;
  __syncthreads();
  for (int i = tid; i < N_SEG; i += 1024) {
    int len = seg_end[i] - seg_start[i];
    int b = len < 2047 ? len : 2047;
    atomicAdd(&A_[b], 1);
  }
  __syncthreads();
  // inclusive suffix sum S[i] = sum_{j>=i} hist[j]
  int* src = A_;
  int* dst = B_;
  for (int d = 1; d < 2048; d <<= 1) {
    for (int i = tid; i < 2048; i += 1024) {
      int v = src[i];
      if (i + d < 2048) v += src[i + d];
      dst[i] = v;
    }
    __syncthreads();
    int* t_ = src; src = dst; dst = t_;
  }
  // dst is free; loc[b] = S[b+1]
  for (int i = tid; i < 2048; i += 1024)
    dst[i] = (i + 1 < 2048) ? src[i + 1] : 0;
  __syncthreads();
  for (int i = tid; i < N_SEG; i += 1024) {
    int len = seg_end[i] - seg_start[i];
    int b = len < 2047 ? len : 2047;
    int pos = atomicAdd(&dst[b], 1);
    sorted_ids[pos] = i;
  }
}

// ---------------- generic bf16 MFMA GEMM: C = ((A @ B^T) + bias) * oscale ----------------
template<bool BF16OUT>
__global__ __launch_bounds__(256) void gemm_bt_kernel(
    const float* __restrict__ A, const float* __restrict__ B0, const float* __restrict__ B1,
    int nsplit, const float* __restrict__ bias0, const float* __restrict__ bias1,
    int K, void* __restrict__ C, int ldc, float oscale) {
  __shared__ unsigned short As[128][40];
  __shared__ unsigned short Bs[128][40];
  const int tid = threadIdx.x;
  const int m0 = blockIdx.x * 128, n0 = blockIdx.y * 128;
  const int wave = tid >> 6, lane = tid & 63;
  const int wm = (wave >> 1) * 64, wn = (wave & 1) * 64;
  const int rowA = lane & 15, kgrp = lane >> 4;
  const int lrow = tid >> 1, lkc = (tid & 1) * 16;

  f32x4 acc[4][4];
#pragma unroll
  for (int i = 0; i < 4; ++i)
#pragma unroll
    for (int j = 0; j < 4; ++j) acc[i][j] = (f32x4){0.f, 0.f, 0.f, 0.f};

  for (int k0 = 0; k0 < K; k0 += 32) {
    __syncthreads();
    {
      const float* ap = A + (size_t)(m0 + lrow) * K + k0 + lkc;
      unsigned short pa[16];
#pragma unroll
      for (int q = 0; q < 4; ++q) {
        float4 v = *(const float4*)(ap + q * 4);
        pa[q * 4 + 0] = f2b(v.x); pa[q * 4 + 1] = f2b(v.y);
        pa[q * 4 + 2] = f2b(v.z); pa[q * 4 + 3] = f2b(v.w);
      }
      *(short8*)&As[lrow][lkc] = *(short8*)&pa[0];
      *(short8*)&As[lrow][lkc + 8] = *(short8*)&pa[8];

      int n = n0 + lrow;
      const float* bp;
      if (n < nsplit) bp = B0 + (size_t)n * K;
      else            bp = B1 + (size_t)(n - nsplit) * K;
      bp += k0 + lkc;
      unsigned short pb[16];
#pragma unroll
      for (int q = 0; q < 4; ++q) {
        float4 v = *(const float4*)(bp + q * 4);
        pb[q * 4 + 0] = f2b(v.x); pb[q * 4 + 1] = f2b(v.y);
        pb[q * 4 + 2] = f2b(v.z); pb[q * 4 + 3] = f2b(v.w);
      }
      *(short8*)&Bs[lrow][lkc] = *(short8*)&pb[0];
      *(short8*)&Bs[lrow][lkc + 8] = *(short8*)&pb[8];
    }
    __syncthreads();
    short8 af[4], bf[4];
#pragma unroll
    for (int mt = 0; mt < 4; ++mt) af[mt] = *(const short8*)&As[wm + mt * 16 + rowA][kgrp * 8];
#pragma unroll
    for (int nt = 0; nt < 4; ++nt) bf[nt] = *(const short8*)&Bs[wn + nt * 16 + rowA][kgrp * 8];
#pragma unroll
    for (int mt = 0; mt < 4; ++mt)
#pragma unroll
      for (int nt = 0; nt < 4; ++nt)
        acc[mt][nt] = __builtin_amdgcn_mfma_f32_16x16x32_bf16(af[mt], bf[nt], acc[mt][nt], 0, 0, 0);
  }

#pragma unroll
  for (int mt = 0; mt < 4; ++mt)
#pragma unroll
    for (int nt = 0; nt < 4; ++nt) {
      int n = n0 + wn + nt * 16 + rowA;
      float bv = (n < nsplit) ? bias0[n] : bias1[n - nsplit];
#pragma unroll
      for (int r = 0; r < 4; ++r) {
        int m = m0 + wm + mt * 16 + kgrp * 4 + r;
        float v = (acc[mt][nt][r] + bv) * oscale;
        if (BF16OUT) ((unsigned short*)C)[(size_t)m * ldc + n] = f2b(v);
        else         ((float*)C)[(size_t)m * ldc + n] = v;
      }
    }
}

// ---------------- scan: transposed MFMA (W=A, h=B), 1 barrier/step, pipelined pre ----------------
// grid (128, 2), block 512 (8 waves). Wave w owns dims [w*64, w*64+64).
// Thread: chain = lane&15, dims = dbase + mt*16 + kgrp*4 + r.
__global__ __launch_bounds__(512, 2) void scan_i8t_kernel(
    const unsigned short* __restrict__ pre,   // [T][1024] bf16, pre-scaled by 2*log2(e)
    const signed char* __restrict__ W8,
    const int* __restrict__ sorted_ids, const int* __restrict__ seg_start_g,
    const int* __restrict__ seg_end_g, float* __restrict__ out) {
  const int dir = blockIdx.y, bb = blockIdx.x;
  const int tid = threadIdx.x;
  const int wave = tid >> 6, lane = tid & 63;
  const int chain = lane & 15, kgrp = lane >> 4;
  const int dbase = wave * 64;

  __shared__ signed char H[2][16][HSTR];
  __shared__ int s_start[16], s_len[16], s_sid[16];

  if (tid < 16) {
    int sid = sorted_ids[bb * 16 + tid];
    s_sid[tid] = sid;
    int st = seg_start_g[sid];
    s_start[tid] = st;
    s_len[tid] = seg_end_g[sid] - st;
  }
  for (int i = tid; i < 16 * 128; i += 512) {   // zero H[0]: 16 rows x 512B
    int r = i >> 7, o = (i & 127) << 2;
    *(int*)&H[0][r][o] = 0;
  }

  // weights into registers: wave's 64 dims x 512 k = 64 fragments x 8B
  long wreg[4][16];
  {
    const signed char* wb = W8 + (((size_t)(dir * 32 + wave * 4)) * 16) * 512 + (size_t)lane * 8;
#pragma unroll
    for (int mt = 0; mt < 4; ++mt)
#pragma unroll
      for (int kt = 0; kt < 16; ++kt)
        wreg[mt][kt] = *(const long*)(wb + (size_t)(mt * 16 + kt) * 512);
  }
  __syncthreads();

  int maxlen = 0;
#pragma unroll
  for (int c = 0; c < 16; ++c) maxlen = maxlen > s_len[c] ? maxlen : s_len[c];
  const int myLen = s_len[chain], myStart = s_start[chain];
  const int sid = s_sid[chain];

  const unsigned short* __restrict__ pb = pre + (size_t)dir * 512 + dbase + kgrp * 4;

  uint2 puA[4], puB[4];
  {
    int t = dir ? (myStart + myLen - 1) : myStart;
    const unsigned short* p = pb + (size_t)t * 1024;
#pragma unroll
    for (int mt = 0; mt < 4; ++mt) puA[mt] = *(const uint2*)(p + mt * 16);
  }

  float pool[4][4];
#pragma unroll
  for (int mt = 0; mt < 4; ++mt)
#pragma unroll
    for (int r = 0; r < 4; ++r) pool[mt][r] = 0.f;

  int cur = 0;
  for (int s = 0; s < maxlen; ++s) {
    // prefetch pre for step s+1 (consumed next iteration; full step of latency hiding)
    {
      int sn = (s + 1 < myLen) ? (s + 1) : (myLen - 1);
      int t = dir ? (myStart + myLen - 1 - sn) : (myStart + sn);
      const unsigned short* p = pb + (size_t)t * 1024;
#pragma unroll
      for (int mt = 0; mt < 4; ++mt) puB[mt] = *(const uint2*)(p + mt * 16);
    }

    i32x4 acc[4];
#pragma unroll
    for (int mt = 0; mt < 4; ++mt) acc[mt] = (i32x4){0, 0, 0, 0};
#pragma unroll
    for (int kt = 0; kt < 16; ++kt) {
      long hb = *(const long*)&H[cur][chain][kt * 32 + kgrp * 8];
#pragma unroll
      for (int mt = 0; mt < 4; ++mt)
        acc[mt] = __builtin_amdgcn_mfma_i32_16x16x32_i8(wreg[mt][kt], hb, acc[mt], 0, 0, 0);
    }

    const float msk = (s < myLen) ? 1.f : 0.f;
#pragma unroll
    for (int mt = 0; mt < 4; ++mt) {
      float p2[4];
      p2[0] = __uint_as_float(puA[mt].x << 16);
      p2[1] = __uint_as_float(puA[mt].x & 0xFFFF0000u);
      p2[2] = __uint_as_float(puA[mt].y << 16);
      p2[3] = __uint_as_float(puA[mt].y & 0xFFFF0000u);
      int q[4];
#pragma unroll
      for (int r = 0; r < 4; ++r) {
        float x2 = fmaf((float)acc[mt][r], DEQ2, p2[r]);   // = 2*log2(e)*tanh_arg
        float e = EXP2F(x2);                                // exp(2x)
        float rc = RCPF(e + 1.f);
        float h = fmaf(-2.f, rc, 1.f);                      // tanh(x)
        pool[mt][r] = fmaf(h, msk, pool[mt][r]);
        q[r] = (int)rintf(fmaf(-254.f, rc, 127.f));         // round(h*127)
      }
      unsigned int pk = (unsigned)(q[0] & 255) | ((unsigned)(q[1] & 255) << 8) |
                        ((unsigned)(q[2] & 255) << 16) | ((unsigned)q[3] << 24);
      *(unsigned int*)&H[cur ^ 1][chain][dbase + mt * 16 + kgrp * 4] = pk;
    }
    __syncthreads();
#pragma unroll
    for (int mt = 0; mt < 4; ++mt) puA[mt] = puB[mt];
    cur ^= 1;
  }

  const float inv = 1.0f / (float)myLen;
  float* op = out + (size_t)sid * OUTW + DPROJ + dir * DLSTM + dbase + kgrp * 4;
#pragma unroll
  for (int mt = 0; mt < 4; ++mt)
    *(float4*)(op + mt * 16) = make_float4(pool[mt][0] * inv, pool[mt][1] * inv,
                                           pool[mt][2] * inv, pool[mt][3] * inv);
}

extern "C" void kernel_launch(void* const* d_in, const int* in_sizes, int n_in,
                              void* d_out, int out_size, void* d_ws, size_t ws_size,
                              hipStream_t stream) {
  const float* x     = (const float*)d_in[0];
  const float* seqs  = (const float*)d_in[1];
  const int*   masks = (const int*)d_in[2];
  const float* Wih_f = (const float*)d_in[3];
  const float* Whh_f = (const float*)d_in[4];
  const float* b_f   = (const float*)d_in[5];
  const float* Wih_b = (const float*)d_in[6];
  const float* Whh_b = (const float*)d_in[7];
  const float* b_b   = (const float*)d_in[8];
  const float* Wx    = (const float*)d_in[9];
  const float* bx    = (const float*)d_in[10];
  float* out = (float*)d_out;

  char* ws = (char*)d_ws;
  const size_t pre_bytes = (size_t)T_N * 1024 * 2;   // 67.1 MB
  const size_t w8_bytes  = (size_t)2 * 512 * 512;    // 0.5 MB
  unsigned short* pre = (unsigned short*)ws;
  signed char* W8     = (signed char*)(ws + pre_bytes);
  int* seg_start      = (int*)(ws + pre_bytes + w8_bytes);
  int* seg_end        = seg_start + N_SEG;
  int* sorted_ids     = seg_end + N_SEG;

  prep_kernel<<<T_N / 256 + 256, 256, 0, stream>>>(masks, seg_start, seg_end, Whh_f, Whh_b, W8);
  csort_kernel<<<1, 1024, 0, stream>>>(seg_start, seg_end, sorted_ids);
  // pre = (seqs @ [Wih_f;Wih_b]^T + [b_f;b_b]) * 2*log2(e), bf16
  gemm_bt_kernel<true><<<dim3(T_N / 128, 1024 / 128), 256, 0, stream>>>(
      seqs, Wih_f, Wih_b, 512, b_f, b_b, DSEQ, pre, 1024, LOG2E2);
  // out[:,0:1024] = x @ Wx^T + bx, f32
  gemm_bt_kernel<false><<<dim3(N_SEG / 128, 1024 / 128), 256, 0, stream>>>(
      x, Wx, nullptr, 1 << 30, bx, nullptr, DX, out, OUTW, 1.0f);
  scan_i8t_kernel<<<dim3(N_SEG / 16, 2), 512, 0, stream>>>(
      pre, W8, sorted_ids, seg_start, seg_end, out);
}